// Round 11
// baseline (93.817 us; speedup 1.0000x reference)
//
#include <hip/hip_runtime.h>
#include <math.h>

#define B 8
#define S 1024
#define L 2048
#define D 1024
#define CH 128  // chunks per batch, 16 rows each

// ---- workspace layout (floats) ----
#define WS_E 0          // [B*L]     unnormalized exp scores (0 if masked)
#define WS_CS 16384     // [B*CH]    per-chunk e-sums
#define WS_PCW 17408    // [B*CH]    per-chunk part·w2 dots
#define WS_INV 18432    // [B]       1/sum(e)
#define WS_CW 18440     // [B]       ctx·w2 (normalized)
#define WS_CTXN 18448   // [B*D]     normalized context
#define WS_PART 26640   // [B*CH*D]  partial unnormalized ctx
#define WS_CNT_BYTE ((26640 + B * CH * D) * 4)  // int cnt[B*4]

typedef float f4v __attribute__((ext_vector_type(4)));
__device__ __forceinline__ void nt_store4(float4* p, float4 v) {
    __builtin_nontemporal_store(*(f4v*)&v, (f4v*)p);
}

__device__ __forceinline__ float dot4(float4 a, float4 b) {
    return a.x * b.x + a.y * b.y + a.z * b.z + a.w * b.w;
}

__device__ __forceinline__ float wave_sum(float v) {
#pragma unroll
    for (int off = 32; off > 0; off >>= 1) v += __shfl_xor(v, off, 64);
    return v;
}

// K1: 1024 blocks, one 16-row chunk each (4 rows/wave, batched for ILP).
// Tail: per-(b,quarter) arrival counters; 128th arriver reduces part->ctxn.
__global__ __launch_bounds__(256) void k_enc(const float* __restrict__ enc,
                                             const int* __restrict__ mask,
                                             const float* __restrict__ w_ptr,
                                             const float* __restrict__ b_ptr,
                                             const float* __restrict__ w_pgen,
                                             float* __restrict__ ws,
                                             int* __restrict__ cnt) {
    __shared__ float lds[4 * D];
    __shared__ float redc[4], redp[4];
    __shared__ int swon[4];
    float4* lds4 = (float4*)lds;
    const int t = threadIdx.x;
    const int w = t >> 6, l = t & 63;
    const int b = blockIdx.x >> 7;
    const int ch = blockIdx.x & 127;
    const int rowbase = b * L + ch * 16 + w * 4;
    const int mymask = mask[rowbase + (l & 3)];
    const float4* wp = (const float4*)(w_ptr + D);
    float4 u0 = wp[l], u1 = wp[l + 64], u2 = wp[l + 128], u3 = wp[l + 192];
    float bp = b_ptr[0];

    // batch-load all 4 rows of this wave
    float4 X0[4], X1[4], X2[4], X3[4];
    int mk[4];
#pragma unroll
    for (int j = 0; j < 4; ++j) {
        mk[j] = __shfl(mymask, j, 64);
        if (mk[j]) {
            const float4* rp = (const float4*)(enc + (size_t)(rowbase + j) * D);
            X0[j] = rp[l]; X1[j] = rp[l + 64];
            X2[j] = rp[l + 128]; X3[j] = rp[l + 192];
        } else {
            float4 z = make_float4(0, 0, 0, 0);
            X0[j] = z; X1[j] = z; X2[j] = z; X3[j] = z;
        }
    }
    // 4 independent dot+reduce chains, interleaved
    float pd[4];
#pragma unroll
    for (int j = 0; j < 4; ++j)
        pd[j] = dot4(X0[j], u0) + dot4(X1[j], u1) + dot4(X2[j], u2) +
                dot4(X3[j], u3);
#pragma unroll
    for (int off = 32; off > 0; off >>= 1) {
#pragma unroll
        for (int j = 0; j < 4; ++j) pd[j] += __shfl_xor(pd[j], off, 64);
    }
    float4 a0 = make_float4(0, 0, 0, 0), a1 = a0, a2 = a0, a3 = a0;
    float es[4];
    float esum_w = 0.f;
#pragma unroll
    for (int j = 0; j < 4; ++j) {
        es[j] = mk[j] ? expf(pd[j] + bp) : 0.f;
        esum_w += es[j];
        if (mk[j]) {
            float e = es[j];
            a0.x += e * X0[j].x; a0.y += e * X0[j].y; a0.z += e * X0[j].z; a0.w += e * X0[j].w;
            a1.x += e * X1[j].x; a1.y += e * X1[j].y; a1.z += e * X1[j].z; a1.w += e * X1[j].w;
            a2.x += e * X2[j].x; a2.y += e * X2[j].y; a2.z += e * X2[j].z; a2.w += e * X2[j].w;
            a3.x += e * X3[j].x; a3.y += e * X3[j].y; a3.z += e * X3[j].z; a3.w += e * X3[j].w;
        }
    }
    if (l == 0) {
#pragma unroll
        for (int j = 0; j < 4; ++j) ws[WS_E + rowbase + j] = es[j];
    }
    // cross-wave part reduce
    float4* lp = lds4 + w * 256;
    lp[l] = a0; lp[l + 64] = a1; lp[l + 128] = a2; lp[l + 192] = a3;
    if (l == 0) redc[w] = esum_w;
    __syncthreads();
    float4 s0 = lds4[t], s1 = lds4[256 + t], s2 = lds4[512 + t], s3 = lds4[768 + t];
    float4 r;
    r.x = (s0.x + s1.x) + (s2.x + s3.x);
    r.y = (s0.y + s1.y) + (s2.y + s3.y);
    r.z = (s0.z + s1.z) + (s2.z + s3.z);
    r.w = (s0.w + s1.w) + (s2.w + s3.w);
    ((float4*)(ws + WS_PART))[(b * CH + ch) * 256 + t] = r;
    float4 w2v = ((const float4*)(w_pgen + D))[t];
    float pc = wave_sum(dot4(r, w2v));
    if (l == 0) redp[w] = pc;
    __syncthreads();
    if (t == 0) {
        ws[WS_CS + b * CH + ch] = (redc[0] + redc[1]) + (redc[2] + redc[3]);
        ws[WS_PCW + b * CH + ch] = (redp[0] + redp[1]) + (redp[2] + redp[3]);
    }
    __syncthreads();
    // arrival counters; last arriver per (b,q) reduces that quarter
    if (t == 0) {
        __builtin_amdgcn_fence(__ATOMIC_RELEASE, "agent");
#pragma unroll
        for (int q = 0; q < 4; ++q)
            swon[q] = (__hip_atomic_fetch_add(&cnt[b * 4 + q], 1,
                                              __ATOMIC_RELAXED,
                                              __HIP_MEMORY_SCOPE_AGENT) ==
                       CH - 1);
    }
    __syncthreads();
    if (!(swon[0] | swon[1] | swon[2] | swon[3])) return;
    if (t == 0) __builtin_amdgcn_fence(__ATOMIC_ACQUIRE, "agent");
    __syncthreads();
    const float4* part4 = (const float4*)(ws + WS_PART);
    float inv;
    {
        float v = ws[WS_CS + b * CH + l] + ws[WS_CS + b * CH + 64 + l];
        inv = 1.0f / wave_sum(v);
    }
    for (int q = 0; q < 4; ++q) {
        if (!swon[q]) continue;
        int chg = t >> 6, d4 = t & 63;
        float4 c = make_float4(0, 0, 0, 0);
#pragma unroll 8
        for (int kk = 0; kk < 32; ++kk) {
            float4 p = part4[(b * CH + chg + 4 * kk) * 256 + q * 64 + d4];
            c.x += p.x; c.y += p.y; c.z += p.z; c.w += p.w;
        }
        lds4[chg * 64 + d4] = c;
        __syncthreads();
        if (t < 64) {
            float4 a0q = lds4[t], a1q = lds4[64 + t], a2q = lds4[128 + t],
                   a3q = lds4[192 + t];
            float4 cx;
            cx.x = ((a0q.x + a1q.x) + (a2q.x + a3q.x)) * inv;
            cx.y = ((a0q.y + a1q.y) + (a2q.y + a3q.y)) * inv;
            cx.z = ((a0q.z + a1q.z) + (a2q.z + a3q.z)) * inv;
            cx.w = ((a0q.w + a1q.w) + (a2q.w + a3q.w)) * inv;
            ((float4*)(ws + WS_CTXN))[b * 256 + q * 64 + t] = cx;
        }
        if (q == 0 && w == 0) {
            float pv = ws[WS_PCW + b * CH + l] + ws[WS_PCW + b * CH + 64 + l];
            float cwu = wave_sum(pv);
            if (l == 0) {
                ws[WS_INV + b] = inv;
                ws[WS_CW + b] = inv * cwu;
            }
        }
        __syncthreads();
    }
}

// K2: 3328 blocks, roles interleaved by bid%13:
//   r in [0,8):  D — 4 dec rows -> out1 (cw is a scalar load now)
//   r in [8,12): A — out0: 8 pw rows (inv is a scalar load)
//   r == 12:     B — out2: pure ctxn broadcast (1 KB read, 128 KB write)
__global__ __launch_bounds__(256) void k_out(const float* __restrict__ ws,
                                             const float* __restrict__ dec,
                                             const float* __restrict__ w_pgen,
                                             const float* __restrict__ b_pgen,
                                             float* __restrict__ out) {
    __shared__ float4 lds4[512];
    const int t = threadIdx.x;
    const int w = t >> 6, l = t & 63;
    const int g = blockIdx.x / 13;
    const int r = blockIdx.x % 13;
    const float4* e4 = (const float4*)(ws + WS_E);
    float4* out0 = (float4*)out;
    float* out1 = out + (size_t)B * S * L;
    float4* out2 = (float4*)(out + (size_t)B * S * L + B * S);

    if (r < 8) {
        // ---- D-unit: 4 dec rows -> out1 ----
        int du = g * 8 + r;  // [0,2048)
        int b = du >> 8;
        float cw = ws[WS_CW + b];
        const float4* w1 = (const float4*)(w_pgen);
        const float4* w3 = (const float4*)(w_pgen + 2 * D);
        float4 c0, c1, c2, c3;
        {
            float4 x, y;
            x = w1[l];       y = w3[l];       c0 = make_float4(x.x + y.x, x.y + y.y, x.z + y.z, x.w + y.w);
            x = w1[l + 64];  y = w3[l + 64];  c1 = make_float4(x.x + y.x, x.y + y.y, x.z + y.z, x.w + y.w);
            x = w1[l + 128]; y = w3[l + 128]; c2 = make_float4(x.x + y.x, x.y + y.y, x.z + y.z, x.w + y.w);
            x = w1[l + 192]; y = w3[l + 192]; c3 = make_float4(x.x + y.x, x.y + y.y, x.z + y.z, x.w + y.w);
        }
        float bpg = b_pgen[0];
        int row = du * 4 + w;  // [0, B*S)
        const float4* rp = (const float4*)(dec + (size_t)row * D);
        float acc = dot4(rp[l], c0) + dot4(rp[l + 64], c1) +
                    dot4(rp[l + 128], c2) + dot4(rp[l + 192], c3);
        acc = wave_sum(acc);
        if (l == 0) out1[row] = 1.0f / (1.0f + expf(-((acc + bpg) + cw)));
    } else if (r < 12) {
        // ---- A-unit: out0 pw rows (b, a of 8 s-rows) ----
        int au = g * 4 + (r - 8);  // [0,1024)
        int b = au >> 7;
        int a = au & 127;
        float invv = ws[WS_INV + b];
        float4 v1 = e4[b * 512 + t], v2 = e4[b * 512 + 256 + t];
        float4 p1, p2;
        p1.x = v1.x * invv; p1.y = v1.y * invv; p1.z = v1.z * invv; p1.w = v1.w * invv;
        p2.x = v2.x * invv; p2.y = v2.y * invv; p2.z = v2.z * invv; p2.w = v2.w * invv;
        lds4[t] = p1;
        lds4[256 + t] = p2;
        __syncthreads();
#pragma unroll 8
        for (int it = 0; it < 16; ++it) {
            int flat = it * 256 + t;
            int s_loc = flat >> 9;
            int l4 = flat & 511;
            nt_store4(&out0[((size_t)(b * S + a * 8 + s_loc)) * 512 + l4],
                      lds4[l4]);
        }
    } else {
        // ---- B-unit: out2 quarter (b, ds) for 128 s-rows (ss) ----
        int bu = g;  // [0,256)
        int b = bu >> 5;
        int q = bu & 31;
        int ds = q & 3;
        int ss = q >> 2;
        if (t < 64)
            lds4[256 + t] = ((const float4*)(ws + WS_CTXN))[b * 256 + ds * 64 + t];
        __syncthreads();
#pragma unroll 8
        for (int it = 0; it < 32; ++it) {
            int flat = it * 256 + t;
            int s_loc = flat >> 6;
            int dloc = flat & 63;
            nt_store4(&out2[((size_t)(b * S + ss * 128 + s_loc)) * 256 +
                            ds * 64 + dloc],
                      lds4[256 + dloc]);
        }
    }
}

extern "C" void kernel_launch(void* const* d_in, const int* in_sizes, int n_in,
                              void* d_out, int out_size, void* d_ws, size_t ws_size,
                              hipStream_t stream) {
    (void)in_sizes; (void)n_in; (void)out_size; (void)ws_size;
    const float* dec = (const float*)d_in[0];
    const float* enc = (const float*)d_in[1];
    const int* mask = (const int*)d_in[2];
    const float* w_ptr = (const float*)d_in[4];
    const float* b_ptr = (const float*)d_in[5];
    const float* w_pgen = (const float*)d_in[6];
    const float* b_pgen = (const float*)d_in[7];
    float* out = (float*)d_out;
    float* ws = (float*)d_ws;
    int* cnt = (int*)((char*)d_ws + WS_CNT_BYTE);

    hipMemsetAsync(cnt, 0, B * 4 * sizeof(int), stream);
    k_enc<<<B * CH, 256, 0, stream>>>(enc, mask, w_ptr, b_ptr, w_pgen, ws, cnt);
    k_out<<<3328, 256, 0, stream>>>(ws, dec, w_pgen, b_pgen, out);
}

// Round 12
// 38.046 us; speedup vs baseline: 2.4659x; 2.4659x over previous
//
#include <hip/hip_runtime.h>
#include <math.h>

#define B 8
#define S 1024
#define L 2048
#define D 1024
#define CH 128  // chunks per batch, 16 rows each

// ---- workspace layout (floats) ----
#define WS_E 0        // [B*L]     unnormalized exp scores (0 if masked)
#define WS_CS 16384   // [B*CH]    per-chunk e-sums (fixed-order partials)
#define WS_PCW 17408  // [B*CH]    per-chunk part·w2 dots
#define WS_PART 18432 // [B*CH*D]  partial unnormalized ctx

typedef float f4v __attribute__((ext_vector_type(4)));
__device__ __forceinline__ void nt_store4(float4* p, float4 v) {
    __builtin_nontemporal_store(*(f4v*)&v, (f4v*)p);
}

__device__ __forceinline__ float dot4(float4 a, float4 b) {
    return a.x * b.x + a.y * b.y + a.z * b.z + a.w * b.w;
}

__device__ __forceinline__ float wave_sum(float v) {
#pragma unroll
    for (int off = 32; off > 0; off >>= 1) v += __shfl_xor(v, off, 64);
    return v;
}

// per-b 1/sum over CH=128 fixed-order chunk sums
__device__ __forceinline__ float sum128(const float* p, int b, int l) {
    return wave_sum(p[b * CH + l] + p[b * CH + 64 + l]);
}

// K1: enc-only. 1024 blocks (4/CU), one 16-row chunk each; 4 rows/wave with the
// proven named-register 2-deep pipeline (row jj+1 loads issued before row jj math).
__global__ __launch_bounds__(256) void k_enc(const float* __restrict__ enc,
                                             const int* __restrict__ mask,
                                             const float* __restrict__ w_ptr,
                                             const float* __restrict__ b_ptr,
                                             const float* __restrict__ w_pgen,
                                             float* __restrict__ ws) {
    __shared__ float lds[4 * D];
    __shared__ float redc[4], redp[4];
    float4* lds4 = (float4*)lds;
    const int t = threadIdx.x;
    const int w = t >> 6, l = t & 63;
    const int b = blockIdx.x >> 7;
    const int ch = blockIdx.x & 127;
    const int rowbase = b * L + ch * 16 + w * 4;
    // all 4 row-masks for this wave, broadcast from lanes 0..3
    const int mymask = mask[rowbase + (l & 3)];
    const float4* wp = (const float4*)(w_ptr + D);
    float4 u0 = wp[l], u1 = wp[l + 64], u2 = wp[l + 128], u3 = wp[l + 192];
    float bp = b_ptr[0];
    float4 a0 = make_float4(0, 0, 0, 0), a1 = a0, a2 = a0, a3 = a0;
    float esum_w = 0.f;
    float4 c0, c1, c2, c3;
    int mc = __shfl(mymask, 0, 64);
    {
        const float4* rp = (const float4*)(enc + (size_t)rowbase * D);
        if (mc) { c0 = rp[l]; c1 = rp[l + 64]; c2 = rp[l + 128]; c3 = rp[l + 192]; }
    }
#pragma unroll
    for (int jj = 0; jj < 4; ++jj) {
        int mn = 0;
        float4 n0, n1, n2, n3;
        if (jj < 3) {
            mn = __shfl(mymask, jj + 1, 64);
            if (mn) {
                const float4* rp =
                    (const float4*)(enc + (size_t)(rowbase + jj + 1) * D);
                n0 = rp[l]; n1 = rp[l + 64]; n2 = rp[l + 128]; n3 = rp[l + 192];
            }
        }
        float e = 0.f;
        if (mc) {
            float pd = dot4(c0, u0) + dot4(c1, u1) + dot4(c2, u2) + dot4(c3, u3);
#pragma unroll
            for (int off = 32; off > 0; off >>= 1) pd += __shfl_xor(pd, off, 64);
            e = expf(pd + bp);
            a0.x += e * c0.x; a0.y += e * c0.y; a0.z += e * c0.z; a0.w += e * c0.w;
            a1.x += e * c1.x; a1.y += e * c1.y; a1.z += e * c1.z; a1.w += e * c1.w;
            a2.x += e * c2.x; a2.y += e * c2.y; a2.z += e * c2.z; a2.w += e * c2.w;
            a3.x += e * c3.x; a3.y += e * c3.y; a3.z += e * c3.z; a3.w += e * c3.w;
        }
        esum_w += e;
        if (l == 0) ws[WS_E + rowbase + jj] = e;
        mc = mn; c0 = n0; c1 = n1; c2 = n2; c3 = n3;
    }
    float4* lp = lds4 + w * 256;
    lp[l] = a0; lp[l + 64] = a1; lp[l + 128] = a2; lp[l + 192] = a3;
    if (l == 0) redc[w] = esum_w;
    __syncthreads();
    float4 s0 = lds4[t], s1 = lds4[256 + t], s2 = lds4[512 + t], s3 = lds4[768 + t];
    float4 r;
    r.x = (s0.x + s1.x) + (s2.x + s3.x);
    r.y = (s0.y + s1.y) + (s2.y + s3.y);
    r.z = (s0.z + s1.z) + (s2.z + s3.z);
    r.w = (s0.w + s1.w) + (s2.w + s3.w);
    ((float4*)(ws + WS_PART))[(b * CH + ch) * 256 + t] = r;
    // pcw: this chunk's contribution to ctx·w2 (fixed-order)
    float4 w2v = ((const float4*)(w_pgen + D))[t];
    float pc = wave_sum(dot4(r, w2v));
    if (l == 0) redp[w] = pc;
    __syncthreads();
    if (t == 0) {
        ws[WS_CS + b * CH + ch] = (redc[0] + redc[1]) + (redc[2] + redc[3]);
        ws[WS_PCW + b * CH + ch] = (redp[0] + redp[1]) + (redp[2] + redp[3]);
    }
}

// K2: 3328 blocks, roles interleaved by bid%13 so dec reads co-flow with writes:
//   r in [0,8):  D — 4 dec rows -> out1 (cw recomputed from cs/pcw scalars)
//   r in [8,12): A — out0: 8 pw rows (64 KB nt-stores)
//   r == 12:     B — out2: quarter-tile, 128 s-rows (128 KB nt-stores)
__global__ __launch_bounds__(256) void k_out(const float* __restrict__ ws,
                                             const float* __restrict__ dec,
                                             const float* __restrict__ w_pgen,
                                             const float* __restrict__ b_pgen,
                                             float* __restrict__ out) {
    __shared__ float4 lds4[512];
    const int t = threadIdx.x;
    const int w = t >> 6, l = t & 63;
    const int g = blockIdx.x / 13;
    const int r = blockIdx.x % 13;
    const float4* e4 = (const float4*)(ws + WS_E);
    const float4* part4 = (const float4*)(ws + WS_PART);
    const float* cs = ws + WS_CS;
    const float* pcw = ws + WS_PCW;
    float4* out0 = (float4*)out;
    float* out1 = out + (size_t)B * S * L;
    float4* out2 = (float4*)(out + (size_t)B * S * L + B * S);

    if (r < 8) {
        // ---- D-unit: 4 dec rows -> out1 ----
        int du = g * 8 + r;  // [0,2048)
        int b = du >> 8;
        float inv = 1.0f / sum128(cs, b, l);
        float cw = inv * sum128(pcw, b, l);
        const float4* w1 = (const float4*)(w_pgen);
        const float4* w3 = (const float4*)(w_pgen + 2 * D);
        float4 c0, c1, c2, c3;
        {
            float4 x, y;
            x = w1[l];       y = w3[l];       c0 = make_float4(x.x + y.x, x.y + y.y, x.z + y.z, x.w + y.w);
            x = w1[l + 64];  y = w3[l + 64];  c1 = make_float4(x.x + y.x, x.y + y.y, x.z + y.z, x.w + y.w);
            x = w1[l + 128]; y = w3[l + 128]; c2 = make_float4(x.x + y.x, x.y + y.y, x.z + y.z, x.w + y.w);
            x = w1[l + 192]; y = w3[l + 192]; c3 = make_float4(x.x + y.x, x.y + y.y, x.z + y.z, x.w + y.w);
        }
        float bpg = b_pgen[0];
        int row = du * 4 + w;  // [0, B*S)
        const float4* rp = (const float4*)(dec + (size_t)row * D);
        float acc = dot4(rp[l], c0) + dot4(rp[l + 64], c1) +
                    dot4(rp[l + 128], c2) + dot4(rp[l + 192], c3);
        acc = wave_sum(acc);
        if (l == 0) out1[row] = 1.0f / (1.0f + expf(-((acc + bpg) + cw)));
    } else if (r < 12) {
        // ---- A-unit: out0 pw rows (b, a of 8 s-rows) ----
        int au = g * 4 + (r - 8);  // [0,1024)
        int b = au >> 7;
        int a = au & 127;
        float inv = 1.0f / sum128(cs, b, l);
        float4 v1 = e4[b * 512 + t], v2 = e4[b * 512 + 256 + t];
        float4 p1, p2;
        p1.x = v1.x * inv; p1.y = v1.y * inv; p1.z = v1.z * inv; p1.w = v1.w * inv;
        p2.x = v2.x * inv; p2.y = v2.y * inv; p2.z = v2.z * inv; p2.w = v2.w * inv;
        lds4[t] = p1;
        lds4[256 + t] = p2;
        __syncthreads();
#pragma unroll 8
        for (int it = 0; it < 16; ++it) {
            int flat = it * 256 + t;
            int s_loc = flat >> 9;
            int l4 = flat & 511;
            nt_store4(&out0[((size_t)(b * S + a * 8 + s_loc)) * 512 + l4],
                      lds4[l4]);
        }
    } else {
        // ---- B-unit: out2 quarter (b, ds) for 128 s-rows (ss) ----
        int bu = g;  // [0,256)
        int b = bu >> 5;
        int q = bu & 31;
        int ds = q & 3;
        int ss = q >> 2;
        float inv = 1.0f / sum128(cs, b, l);
        int d4 = t & 63;
        int chg = t >> 6;
        float4 c = make_float4(0, 0, 0, 0);
#pragma unroll 8
        for (int kk = 0; kk < 32; ++kk) {
            int chx = chg + kk * 4;
            float4 p = part4[(b * CH + chx) * 256 + ds * 64 + d4];
            c.x += p.x; c.y += p.y; c.z += p.z; c.w += p.w;
        }
        lds4[chg * 64 + d4] = c;
        __syncthreads();
        if (t < 64) {
            float4 a0 = lds4[t], a1 = lds4[64 + t], a2 = lds4[128 + t],
                   a3 = lds4[192 + t];
            float4 cx;
            cx.x = ((a0.x + a1.x) + (a2.x + a3.x)) * inv;
            cx.y = ((a0.y + a1.y) + (a2.y + a3.y)) * inv;
            cx.z = ((a0.z + a1.z) + (a2.z + a3.z)) * inv;
            cx.w = ((a0.w + a1.w) + (a2.w + a3.w)) * inv;
            lds4[256 + t] = cx;
        }
        __syncthreads();
#pragma unroll 8
        for (int it = 0; it < 32; ++it) {
            int flat = it * 256 + t;
            int s_loc = flat >> 6;
            int dloc = flat & 63;
            nt_store4(&out2[((size_t)(b * S + ss * 128 + s_loc)) * 256 +
                            ds * 64 + dloc],
                      lds4[256 + dloc]);
        }
    }
}

extern "C" void kernel_launch(void* const* d_in, const int* in_sizes, int n_in,
                              void* d_out, int out_size, void* d_ws, size_t ws_size,
                              hipStream_t stream) {
    (void)in_sizes; (void)n_in; (void)out_size; (void)ws_size;
    const float* dec = (const float*)d_in[0];
    const float* enc = (const float*)d_in[1];
    const int* mask = (const int*)d_in[2];
    const float* w_ptr = (const float*)d_in[4];
    const float* b_ptr = (const float*)d_in[5];
    const float* w_pgen = (const float*)d_in[6];
    const float* b_pgen = (const float*)d_in[7];
    float* out = (float*)d_out;
    float* ws = (float*)d_ws;

    k_enc<<<B * CH, 256, 0, stream>>>(enc, mask, w_ptr, b_ptr, w_pgen, ws);
    k_out<<<3328, 256, 0, stream>>>(ws, dec, w_pgen, b_pgen, out);
}

// Round 13
// 35.265 us; speedup vs baseline: 2.6603x; 1.0789x over previous
//
#include <hip/hip_runtime.h>
#include <math.h>

#define B 8
#define S 1024
#define L 2048
#define D 1024

// ---- workspace layout (floats) ----
#define WS_E 0        // [B*L]    unnormalized exp scores (0 if masked)
#define WS_CS 16384   // [B*64]   per-chunk e-sums (fixed-order partials)
#define WS_PCW 16896  // [B*64]   per-chunk part·w2 dots
#define WS_PART 17408 // [B*64*D] partial unnormalized ctx

typedef float f4v __attribute__((ext_vector_type(4)));
__device__ __forceinline__ void nt_store4(float4* p, float4 v) {
    __builtin_nontemporal_store(*(f4v*)&v, (f4v*)p);
}

__device__ __forceinline__ float dot4(float4 a, float4 b) {
    return a.x * b.x + a.y * b.y + a.z * b.z + a.w * b.w;
}

__device__ __forceinline__ float wave_sum(float v) {
#pragma unroll
    for (int off = 32; off > 0; off >>= 1) v += __shfl_xor(v, off, 64);
    return v;
}

// K1 (identical to R10 best): enc-only, 512 blocks, one (b,ch) 32-row chunk each;
// 8 rows/wave with named-register 2-deep pipeline.
__global__ __launch_bounds__(256) void k_enc(const float* __restrict__ enc,
                                             const int* __restrict__ mask,
                                             const float* __restrict__ w_ptr,
                                             const float* __restrict__ b_ptr,
                                             const float* __restrict__ w_pgen,
                                             float* __restrict__ ws) {
    __shared__ float lds[4 * D];
    __shared__ float redc[4], redp[4];
    float4* lds4 = (float4*)lds;
    const int t = threadIdx.x;
    const int w = t >> 6, l = t & 63;
    const int b = blockIdx.x >> 6;
    const int ch = blockIdx.x & 63;
    const int rowbase = b * L + ch * 32 + w * 8;
    const int mymask = mask[rowbase + (l & 7)];
    const float4* wp = (const float4*)(w_ptr + D);
    float4 u0 = wp[l], u1 = wp[l + 64], u2 = wp[l + 128], u3 = wp[l + 192];
    float bp = b_ptr[0];
    float4 a0 = make_float4(0, 0, 0, 0), a1 = a0, a2 = a0, a3 = a0;
    float esum_w = 0.f;
    float4 c0, c1, c2, c3;
    int mc = __shfl(mymask, 0, 64);
    {
        const float4* rp = (const float4*)(enc + (size_t)rowbase * D);
        if (mc) { c0 = rp[l]; c1 = rp[l + 64]; c2 = rp[l + 128]; c3 = rp[l + 192]; }
    }
#pragma unroll
    for (int jj = 0; jj < 8; ++jj) {
        int mn = 0;
        float4 n0, n1, n2, n3;
        if (jj < 7) {
            mn = __shfl(mymask, jj + 1, 64);
            if (mn) {
                const float4* rp =
                    (const float4*)(enc + (size_t)(rowbase + jj + 1) * D);
                n0 = rp[l]; n1 = rp[l + 64]; n2 = rp[l + 128]; n3 = rp[l + 192];
            }
        }
        float e = 0.f;
        if (mc) {
            float pd = dot4(c0, u0) + dot4(c1, u1) + dot4(c2, u2) + dot4(c3, u3);
#pragma unroll
            for (int off = 32; off > 0; off >>= 1) pd += __shfl_xor(pd, off, 64);
            e = expf(pd + bp);
            a0.x += e * c0.x; a0.y += e * c0.y; a0.z += e * c0.z; a0.w += e * c0.w;
            a1.x += e * c1.x; a1.y += e * c1.y; a1.z += e * c1.z; a1.w += e * c1.w;
            a2.x += e * c2.x; a2.y += e * c2.y; a2.z += e * c2.z; a2.w += e * c2.w;
            a3.x += e * c3.x; a3.y += e * c3.y; a3.z += e * c3.z; a3.w += e * c3.w;
        }
        esum_w += e;
        if (l == 0) ws[WS_E + rowbase + jj] = e;
        mc = mn; c0 = n0; c1 = n1; c2 = n2; c3 = n3;
    }
    float4* lp = lds4 + w * 256;
    lp[l] = a0; lp[l + 64] = a1; lp[l + 128] = a2; lp[l + 192] = a3;
    if (l == 0) redc[w] = esum_w;
    __syncthreads();
    float4 s0 = lds4[t], s1 = lds4[256 + t], s2 = lds4[512 + t], s3 = lds4[768 + t];
    float4 r;
    r.x = (s0.x + s1.x) + (s2.x + s3.x);
    r.y = (s0.y + s1.y) + (s2.y + s3.y);
    r.z = (s0.z + s1.z) + (s2.z + s3.z);
    r.w = (s0.w + s1.w) + (s2.w + s3.w);
    ((float4*)(ws + WS_PART))[(b * 64 + ch) * 256 + t] = r;
    float4 w2v = ((const float4*)(w_pgen + D))[t];
    float pc = wave_sum(dot4(r, w2v));
    if (l == 0) redp[w] = pc;
    __syncthreads();
    if (t == 0) {
        ws[WS_CS + b * 64 + ch] = (redc[0] + redc[1]) + (redc[2] + redc[3]);
        ws[WS_PCW + b * 64 + ch] = (redp[0] + redp[1]) + (redp[2] + redp[3]);
    }
}

// K2: 1792 blocks, %7 interleave (4 D : 2 A : 1 B). Fatter blocks amortize
// prologues and lengthen nt-store bursts.
//   D (1024): 8 dec rows -> out1; cw computed once per block
//   A (512):  16 pw rows (128 KB nt-stores)
//   B (256):  out2 quarter-tile, 128 s-rows (128 KB nt-stores)
__global__ __launch_bounds__(256) void k_out(const float* __restrict__ ws,
                                             const float* __restrict__ dec,
                                             const float* __restrict__ w_pgen,
                                             const float* __restrict__ b_pgen,
                                             float* __restrict__ out) {
    __shared__ float4 lds4[512];
    const int t = threadIdx.x;
    const int w = t >> 6, l = t & 63;
    const int g = blockIdx.x / 7;
    const int r = blockIdx.x % 7;
    const float4* e4 = (const float4*)(ws + WS_E);
    const float4* part4 = (const float4*)(ws + WS_PART);
    const float* cs = ws + WS_CS;
    const float* pcw = ws + WS_PCW;
    float4* out0 = (float4*)out;
    float* out1 = out + (size_t)B * S * L;
    float4* out2 = (float4*)(out + (size_t)B * S * L + B * S);

    if (r < 4) {
        // ---- D-unit: 8 dec rows -> out1 (2 per wave) ----
        int du = g * 4 + r;  // [0,1024)
        int b = du >> 7;
        float inv = 1.0f / wave_sum(cs[b * 64 + l]);
        float cw = inv * wave_sum(pcw[b * 64 + l]);
        const float4* w1 = (const float4*)(w_pgen);
        const float4* w3 = (const float4*)(w_pgen + 2 * D);
        float4 c0, c1, c2, c3;
        {
            float4 x, y;
            x = w1[l];       y = w3[l];       c0 = make_float4(x.x + y.x, x.y + y.y, x.z + y.z, x.w + y.w);
            x = w1[l + 64];  y = w3[l + 64];  c1 = make_float4(x.x + y.x, x.y + y.y, x.z + y.z, x.w + y.w);
            x = w1[l + 128]; y = w3[l + 128]; c2 = make_float4(x.x + y.x, x.y + y.y, x.z + y.z, x.w + y.w);
            x = w1[l + 192]; y = w3[l + 192]; c3 = make_float4(x.x + y.x, x.y + y.y, x.z + y.z, x.w + y.w);
        }
        float bpg = b_pgen[0];
#pragma unroll
        for (int jj = 0; jj < 2; ++jj) {
            int row = du * 8 + w * 2 + jj;  // [0, B*S)
            const float4* rp = (const float4*)(dec + (size_t)row * D);
            float acc = dot4(rp[l], c0) + dot4(rp[l + 64], c1) +
                        dot4(rp[l + 128], c2) + dot4(rp[l + 192], c3);
            acc = wave_sum(acc);
            if (l == 0) out1[row] = 1.0f / (1.0f + expf(-((acc + bpg) + cw)));
        }
    } else if (r < 6) {
        // ---- A-unit: out0 pw rows (b, a of 16 s-rows) ----
        int au = g * 2 + (r - 4);  // [0,512)
        int b = au >> 6;
        int a = au & 63;
        float inv = 1.0f / wave_sum(cs[b * 64 + l]);
        float4 v1 = e4[b * 512 + t], v2 = e4[b * 512 + 256 + t];
        float4 p1, p2;
        p1.x = v1.x * inv; p1.y = v1.y * inv; p1.z = v1.z * inv; p1.w = v1.w * inv;
        p2.x = v2.x * inv; p2.y = v2.y * inv; p2.z = v2.z * inv; p2.w = v2.w * inv;
        lds4[t] = p1;
        lds4[256 + t] = p2;
        __syncthreads();
#pragma unroll 8
        for (int it = 0; it < 32; ++it) {
            int flat = it * 256 + t;
            int s_loc = flat >> 9;
            int l4 = flat & 511;
            nt_store4(&out0[((size_t)(b * S + a * 16 + s_loc)) * 512 + l4],
                      lds4[l4]);
        }
    } else {
        // ---- B-unit: out2 quarter (b, ds) for 128 s-rows (ss) ----
        int bu = g;  // [0,256)
        int b = bu >> 5;
        int q = bu & 31;
        int ds = q & 3;
        int ss = q >> 2;
        float inv = 1.0f / wave_sum(cs[b * 64 + l]);
        int d4 = t & 63;
        int chg = t >> 6;
        float4 c = make_float4(0, 0, 0, 0);
#pragma unroll
        for (int kk = 0; kk < 16; ++kk) {
            int ch = chg + kk * 4;
            float4 p = part4[(b * 64 + ch) * 256 + ds * 64 + d4];
            c.x += p.x; c.y += p.y; c.z += p.z; c.w += p.w;
        }
        lds4[chg * 64 + d4] = c;
        __syncthreads();
        if (t < 64) {
            float4 a0 = lds4[t], a1 = lds4[64 + t], a2 = lds4[128 + t],
                   a3 = lds4[192 + t];
            float4 cx;
            cx.x = ((a0.x + a1.x) + (a2.x + a3.x)) * inv;
            cx.y = ((a0.y + a1.y) + (a2.y + a3.y)) * inv;
            cx.z = ((a0.z + a1.z) + (a2.z + a3.z)) * inv;
            cx.w = ((a0.w + a1.w) + (a2.w + a3.w)) * inv;
            lds4[256 + t] = cx;
        }
        __syncthreads();
#pragma unroll 8
        for (int it = 0; it < 32; ++it) {
            int flat = it * 256 + t;
            int s_loc = flat >> 6;
            int dloc = flat & 63;
            nt_store4(&out2[((size_t)(b * S + ss * 128 + s_loc)) * 256 +
                            ds * 64 + dloc],
                      lds4[256 + dloc]);
        }
    }
}

extern "C" void kernel_launch(void* const* d_in, const int* in_sizes, int n_in,
                              void* d_out, int out_size, void* d_ws, size_t ws_size,
                              hipStream_t stream) {
    (void)in_sizes; (void)n_in; (void)out_size; (void)ws_size;
    const float* dec = (const float*)d_in[0];
    const float* enc = (const float*)d_in[1];
    const int* mask = (const int*)d_in[2];
    const float* w_ptr = (const float*)d_in[4];
    const float* b_ptr = (const float*)d_in[5];
    const float* w_pgen = (const float*)d_in[6];
    const float* b_pgen = (const float*)d_in[7];
    float* out = (float*)d_out;
    float* ws = (float*)d_ws;

    k_enc<<<512, 256, 0, stream>>>(enc, mask, w_ptr, b_ptr, w_pgen, ws);
    k_out<<<1792, 256, 0, stream>>>(ws, dec, w_pgen, b_pgen, out);
}

// Round 14
// 35.150 us; speedup vs baseline: 2.6690x; 1.0033x over previous
//
#include <hip/hip_runtime.h>
#include <math.h>

#define B 8
#define S 1024
#define L 2048
#define D 1024

// ---- workspace layout (floats) ----
#define WS_E 0        // [B*L]    unnormalized exp scores (0 if masked)
#define WS_CS 16384   // [B*64]   per-chunk e-sums (fixed-order partials)
#define WS_PCW 16896  // [B*64]   per-chunk part·w2 dots
#define WS_PART 17408 // [B*64*D] partial unnormalized ctx

typedef float f4v __attribute__((ext_vector_type(4)));
__device__ __forceinline__ void nt_store4(float4* p, float4 v) {
    __builtin_nontemporal_store(*(f4v*)&v, (f4v*)p);
}

__device__ __forceinline__ float dot4(float4 a, float4 b) {
    return a.x * b.x + a.y * b.y + a.z * b.z + a.w * b.w;
}

__device__ __forceinline__ float wave_sum(float v) {
#pragma unroll
    for (int off = 32; off > 0; off >>= 1) v += __shfl_xor(v, off, 64);
    return v;
}

// K1: enc-only, 512 blocks, one (b,ch) 32-row chunk each; 8 rows/wave processed
// as 4 PAIRS: two interleaved independent shfl-reduce chains per pair, next
// pair's loads prefetched (all named registers).
__global__ __launch_bounds__(256) void k_enc(const float* __restrict__ enc,
                                             const int* __restrict__ mask,
                                             const float* __restrict__ w_ptr,
                                             const float* __restrict__ b_ptr,
                                             const float* __restrict__ w_pgen,
                                             float* __restrict__ ws) {
    __shared__ float lds[4 * D];
    __shared__ float redc[4], redp[4];
    float4* lds4 = (float4*)lds;
    const int t = threadIdx.x;
    const int w = t >> 6, l = t & 63;
    const int b = blockIdx.x >> 6;
    const int ch = blockIdx.x & 63;
    const int rowbase = b * L + ch * 32 + w * 8;
    const int mymask = mask[rowbase + (l & 7)];
    const float4* wp = (const float4*)(w_ptr + D);
    float4 u0 = wp[l], u1 = wp[l + 64], u2 = wp[l + 128], u3 = wp[l + 192];
    float bp = b_ptr[0];
    float4 a0 = make_float4(0, 0, 0, 0), a1 = a0, a2 = a0, a3 = a0;
    float esum_w = 0.f;
    // current pair rows in c* (even row) and d* (odd row)
    float4 c0, c1, c2, c3, d0, d1, d2, d3;
    int mc0 = __shfl(mymask, 0, 64);
    int mc1 = __shfl(mymask, 1, 64);
    {
        const float4* rp = (const float4*)(enc + (size_t)rowbase * D);
        if (mc0) { c0 = rp[l]; c1 = rp[l + 64]; c2 = rp[l + 128]; c3 = rp[l + 192]; }
        const float4* rq = (const float4*)(enc + (size_t)(rowbase + 1) * D);
        if (mc1) { d0 = rq[l]; d1 = rq[l + 64]; d2 = rq[l + 128]; d3 = rq[l + 192]; }
    }
#pragma unroll
    for (int p = 0; p < 4; ++p) {
        int mn0 = 0, mn1 = 0;
        float4 n0, n1, n2, n3, m0, m1, m2, m3;
        if (p < 3) {
            mn0 = __shfl(mymask, 2 * p + 2, 64);
            mn1 = __shfl(mymask, 2 * p + 3, 64);
            if (mn0) {
                const float4* rp =
                    (const float4*)(enc + (size_t)(rowbase + 2 * p + 2) * D);
                n0 = rp[l]; n1 = rp[l + 64]; n2 = rp[l + 128]; n3 = rp[l + 192];
            }
            if (mn1) {
                const float4* rq =
                    (const float4*)(enc + (size_t)(rowbase + 2 * p + 3) * D);
                m0 = rq[l]; m1 = rq[l + 64]; m2 = rq[l + 128]; m3 = rq[l + 192];
            }
        }
        // two independent dot+reduce chains, interleaved
        float pd0 = 0.f, pd1 = 0.f;
        if (mc0) pd0 = dot4(c0, u0) + dot4(c1, u1) + dot4(c2, u2) + dot4(c3, u3);
        if (mc1) pd1 = dot4(d0, u0) + dot4(d1, u1) + dot4(d2, u2) + dot4(d3, u3);
#pragma unroll
        for (int off = 32; off > 0; off >>= 1) {
            pd0 += __shfl_xor(pd0, off, 64);
            pd1 += __shfl_xor(pd1, off, 64);
        }
        float e0 = 0.f, e1 = 0.f;
        if (mc0) {
            e0 = expf(pd0 + bp);
            a0.x += e0 * c0.x; a0.y += e0 * c0.y; a0.z += e0 * c0.z; a0.w += e0 * c0.w;
            a1.x += e0 * c1.x; a1.y += e0 * c1.y; a1.z += e0 * c1.z; a1.w += e0 * c1.w;
            a2.x += e0 * c2.x; a2.y += e0 * c2.y; a2.z += e0 * c2.z; a2.w += e0 * c2.w;
            a3.x += e0 * c3.x; a3.y += e0 * c3.y; a3.z += e0 * c3.z; a3.w += e0 * c3.w;
        }
        if (mc1) {
            e1 = expf(pd1 + bp);
            a0.x += e1 * d0.x; a0.y += e1 * d0.y; a0.z += e1 * d0.z; a0.w += e1 * d0.w;
            a1.x += e1 * d1.x; a1.y += e1 * d1.y; a1.z += e1 * d1.z; a1.w += e1 * d1.w;
            a2.x += e1 * d2.x; a2.y += e1 * d2.y; a2.z += e1 * d2.z; a2.w += e1 * d2.w;
            a3.x += e1 * d3.x; a3.y += e1 * d3.y; a3.z += e1 * d3.z; a3.w += e1 * d3.w;
        }
        esum_w += e0;
        esum_w += e1;
        if (l == 0) {
            ws[WS_E + rowbase + 2 * p] = e0;
            ws[WS_E + rowbase + 2 * p + 1] = e1;
        }
        mc0 = mn0; c0 = n0; c1 = n1; c2 = n2; c3 = n3;
        mc1 = mn1; d0 = m0; d1 = m1; d2 = m2; d3 = m3;
    }
    float4* lp = lds4 + w * 256;
    lp[l] = a0; lp[l + 64] = a1; lp[l + 128] = a2; lp[l + 192] = a3;
    if (l == 0) redc[w] = esum_w;
    __syncthreads();
    float4 s0 = lds4[t], s1 = lds4[256 + t], s2 = lds4[512 + t], s3 = lds4[768 + t];
    float4 r;
    r.x = (s0.x + s1.x) + (s2.x + s3.x);
    r.y = (s0.y + s1.y) + (s2.y + s3.y);
    r.z = (s0.z + s1.z) + (s2.z + s3.z);
    r.w = (s0.w + s1.w) + (s2.w + s3.w);
    ((float4*)(ws + WS_PART))[(b * 64 + ch) * 256 + t] = r;
    float4 w2v = ((const float4*)(w_pgen + D))[t];
    float pc = wave_sum(dot4(r, w2v));
    if (l == 0) redp[w] = pc;
    __syncthreads();
    if (t == 0) {
        ws[WS_CS + b * 64 + ch] = (redc[0] + redc[1]) + (redc[2] + redc[3]);
        ws[WS_PCW + b * 64 + ch] = (redp[0] + redp[1]) + (redp[2] + redp[3]);
    }
}

// K2 (identical to R13): 1792 blocks, %7 interleave (4 D : 2 A : 1 B).
//   D (1024): 8 dec rows -> out1; cw computed once per block
//   A (512):  16 pw rows (128 KB nt-stores)
//   B (256):  out2 quarter-tile, 128 s-rows (128 KB nt-stores)
__global__ __launch_bounds__(256) void k_out(const float* __restrict__ ws,
                                             const float* __restrict__ dec,
                                             const float* __restrict__ w_pgen,
                                             const float* __restrict__ b_pgen,
                                             float* __restrict__ out) {
    __shared__ float4 lds4[512];
    const int t = threadIdx.x;
    const int w = t >> 6, l = t & 63;
    const int g = blockIdx.x / 7;
    const int r = blockIdx.x % 7;
    const float4* e4 = (const float4*)(ws + WS_E);
    const float4* part4 = (const float4*)(ws + WS_PART);
    const float* cs = ws + WS_CS;
    const float* pcw = ws + WS_PCW;
    float4* out0 = (float4*)out;
    float* out1 = out + (size_t)B * S * L;
    float4* out2 = (float4*)(out + (size_t)B * S * L + B * S);

    if (r < 4) {
        // ---- D-unit: 8 dec rows -> out1 (2 per wave) ----
        int du = g * 4 + r;  // [0,1024)
        int b = du >> 7;
        float inv = 1.0f / wave_sum(cs[b * 64 + l]);
        float cw = inv * wave_sum(pcw[b * 64 + l]);
        const float4* w1 = (const float4*)(w_pgen);
        const float4* w3 = (const float4*)(w_pgen + 2 * D);
        float4 c0, c1, c2, c3;
        {
            float4 x, y;
            x = w1[l];       y = w3[l];       c0 = make_float4(x.x + y.x, x.y + y.y, x.z + y.z, x.w + y.w);
            x = w1[l + 64];  y = w3[l + 64];  c1 = make_float4(x.x + y.x, x.y + y.y, x.z + y.z, x.w + y.w);
            x = w1[l + 128]; y = w3[l + 128]; c2 = make_float4(x.x + y.x, x.y + y.y, x.z + y.z, x.w + y.w);
            x = w1[l + 192]; y = w3[l + 192]; c3 = make_float4(x.x + y.x, x.y + y.y, x.z + y.z, x.w + y.w);
        }
        float bpg = b_pgen[0];
#pragma unroll
        for (int jj = 0; jj < 2; ++jj) {
            int row = du * 8 + w * 2 + jj;  // [0, B*S)
            const float4* rp = (const float4*)(dec + (size_t)row * D);
            float acc = dot4(rp[l], c0) + dot4(rp[l + 64], c1) +
                        dot4(rp[l + 128], c2) + dot4(rp[l + 192], c3);
            acc = wave_sum(acc);
            if (l == 0) out1[row] = 1.0f / (1.0f + expf(-((acc + bpg) + cw)));
        }
    } else if (r < 6) {
        // ---- A-unit: out0 pw rows (b, a of 16 s-rows) ----
        int au = g * 2 + (r - 4);  // [0,512)
        int b = au >> 6;
        int a = au & 63;
        float inv = 1.0f / wave_sum(cs[b * 64 + l]);
        float4 v1 = e4[b * 512 + t], v2 = e4[b * 512 + 256 + t];
        float4 p1, p2;
        p1.x = v1.x * inv; p1.y = v1.y * inv; p1.z = v1.z * inv; p1.w = v1.w * inv;
        p2.x = v2.x * inv; p2.y = v2.y * inv; p2.z = v2.z * inv; p2.w = v2.w * inv;
        lds4[t] = p1;
        lds4[256 + t] = p2;
        __syncthreads();
#pragma unroll 8
        for (int it = 0; it < 32; ++it) {
            int flat = it * 256 + t;
            int s_loc = flat >> 9;
            int l4 = flat & 511;
            nt_store4(&out0[((size_t)(b * S + a * 16 + s_loc)) * 512 + l4],
                      lds4[l4]);
        }
    } else {
        // ---- B-unit: out2 quarter (b, ds) for 128 s-rows (ss) ----
        int bu = g;  // [0,256)
        int b = bu >> 5;
        int q = bu & 31;
        int ds = q & 3;
        int ss = q >> 2;
        float inv = 1.0f / wave_sum(cs[b * 64 + l]);
        int d4 = t & 63;
        int chg = t >> 6;
        float4 c = make_float4(0, 0, 0, 0);
#pragma unroll
        for (int kk = 0; kk < 16; ++kk) {
            int ch = chg + kk * 4;
            float4 p = part4[(b * 64 + ch) * 256 + ds * 64 + d4];
            c.x += p.x; c.y += p.y; c.z += p.z; c.w += p.w;
        }
        lds4[chg * 64 + d4] = c;
        __syncthreads();
        if (t < 64) {
            float4 a0 = lds4[t], a1 = lds4[64 + t], a2 = lds4[128 + t],
                   a3 = lds4[192 + t];
            float4 cx;
            cx.x = ((a0.x + a1.x) + (a2.x + a3.x)) * inv;
            cx.y = ((a0.y + a1.y) + (a2.y + a3.y)) * inv;
            cx.z = ((a0.z + a1.z) + (a2.z + a3.z)) * inv;
            cx.w = ((a0.w + a1.w) + (a2.w + a3.w)) * inv;
            lds4[256 + t] = cx;
        }
        __syncthreads();
#pragma unroll 8
        for (int it = 0; it < 32; ++it) {
            int flat = it * 256 + t;
            int s_loc = flat >> 6;
            int dloc = flat & 63;
            nt_store4(&out2[((size_t)(b * S + ss * 128 + s_loc)) * 256 +
                            ds * 64 + dloc],
                      lds4[256 + dloc]);
        }
    }
}

extern "C" void kernel_launch(void* const* d_in, const int* in_sizes, int n_in,
                              void* d_out, int out_size, void* d_ws, size_t ws_size,
                              hipStream_t stream) {
    (void)in_sizes; (void)n_in; (void)out_size; (void)ws_size;
    const float* dec = (const float*)d_in[0];
    const float* enc = (const float*)d_in[1];
    const int* mask = (const int*)d_in[2];
    const float* w_ptr = (const float*)d_in[4];
    const float* b_ptr = (const float*)d_in[5];
    const float* w_pgen = (const float*)d_in[6];
    const float* b_pgen = (const float*)d_in[7];
    float* out = (float*)d_out;
    float* ws = (float*)d_ws;

    k_enc<<<512, 256, 0, stream>>>(enc, mask, w_ptr, b_ptr, w_pgen, ws);
    k_out<<<1792, 256, 0, stream>>>(ws, dec, w_pgen, b_pgen, out);
}